// Round 1
// baseline (3926.456 us; speedup 1.0000x reference)
//
#include <hip/hip_runtime.h>

#define N_ROWS 32768
#define DIM    256
#define NE     256
#define KP     4096
#define NQ     4
#define ND     8388608   // N_ROWS*DIM

typedef short short8 __attribute__((ext_vector_type(8)));
typedef float f32x4  __attribute__((ext_vector_type(4)));

__device__ inline float bf2f(unsigned short u) {
  return __uint_as_float(((unsigned)u) << 16);
}
__device__ inline unsigned short f2bf(float f) {
  unsigned u = __float_as_uint(f);
  u += 0x7fffu + ((u >> 16) & 1u);
  return (unsigned short)(u >> 16);
}

// ---------------- init: residual = x ----------------
__global__ void copy_kernel(const float* __restrict__ x, float* __restrict__ resid) {
  size_t i = (size_t)blockIdx.x * blockDim.x + threadIdx.x;  // 8192*256 = ND/4
  ((float4*)resid)[i] = ((const float4*)x)[i];
}

// ---------------- per-stage: row norms + bf16 normalize ----------------
__global__ __launch_bounds__(256) void normalize_kernel(
    const float* __restrict__ resid, unsigned short* __restrict__ Xn,
    float* __restrict__ rnorm) {
  const int wave = threadIdx.x >> 6, lane = threadIdx.x & 63;
  const int row = blockIdx.x * 4 + wave;
  float4 v = ((const float4*)(resid + (size_t)row * DIM))[lane];
  float ss = v.x * v.x + v.y * v.y + v.z * v.z + v.w * v.w;
#pragma unroll
  for (int m = 1; m < 64; m <<= 1) ss += __shfl_xor(ss, m, 64);
  if (lane == 0) rnorm[row] = ss;
  const float sc = rsqrtf(ss + 1e-12f);
  ushort4 o;
  o.x = f2bf(v.x * sc); o.y = f2bf(v.y * sc);
  o.z = f2bf(v.z * sc); o.w = f2bf(v.w * sc);
  ((ushort4*)(Xn + (size_t)row * DIM))[lane] = o;
}

// ---------------- per-stage: gather xn[i1] + pos ----------------
__global__ __launch_bounds__(256) void gather_pos_kernel(
    const unsigned short* __restrict__ Xn, const int* __restrict__ i1,
    const int* __restrict__ i2, unsigned short* __restrict__ Qg,
    float* __restrict__ pos) {
  const int wave = threadIdx.x >> 6, lane = threadIdx.x & 63;
  const int k = blockIdx.x * 4 + wave;
  const int a = i1[k], b = i2[k];
  ushort4 va = ((const ushort4*)(Xn + (size_t)a * DIM))[lane];
  ushort4 vb = ((const ushort4*)(Xn + (size_t)b * DIM))[lane];
  ((ushort4*)(Qg + (size_t)k * DIM))[lane] = va;
  float d = bf2f(va.x) * bf2f(vb.x) + bf2f(va.y) * bf2f(vb.y) +
            bf2f(va.z) * bf2f(vb.z) + bf2f(va.w) * bf2f(vb.w);
#pragma unroll
  for (int m = 1; m < 64; m <<= 1) d += __shfl_xor(d, m, 64);
  if (lane == 0) pos[k] = d * 10.0f;  // /TEMP
}

// ---------------- per-stage: sim GEMM (MFMA bf16) + sum(exp(logit-10)) ----------------
// grid (64 qtiles, 16 n-chunks of 2048), block 256 (4 waves, 16 queries each)
__global__ __launch_bounds__(256) void sim_lse_kernel(
    const unsigned short* __restrict__ Qg, const unsigned short* __restrict__ Xn,
    float* __restrict__ s_sum) {
  const int lane = threadIdx.x & 63;
  const int wave = threadIdx.x >> 6;
  const int quad = lane >> 4;
  const int l16  = lane & 15;
  const int qbase = blockIdx.x * 64 + wave * 16;
  const short8* arow = (const short8*)(Qg + (size_t)(qbase + l16) * DIM + quad * 8);
  short8 a[8];
#pragma unroll
  for (int f = 0; f < 8; ++f) a[f] = arow[f * 4];  // full 16x256 Q-tile in regs
  float s[4] = {0.f, 0.f, 0.f, 0.f};
  const int nb0 = blockIdx.y * 2048;
  const float C1 = 14.4269504088896341f;  // 10*log2(e); exp(10d-10)=exp2(d*C1-C1)
  for (int g = 0; g < 128; ++g) {
    const short8* brow =
        (const short8*)(Xn + (size_t)(nb0 + g * 16 + l16) * DIM + quad * 8);
    f32x4 acc = {0.f, 0.f, 0.f, 0.f};
#pragma unroll
    for (int f = 0; f < 8; ++f)
      acc = __builtin_amdgcn_mfma_f32_16x16x32_bf16(a[f], brow[f * 4], acc, 0, 0, 0);
#pragma unroll
    for (int i = 0; i < 4; ++i) s[i] += exp2f(fmaf(acc[i], C1, -C1));
  }
  // acc row = query quad*4+i, col = xn row l16: sum over the 16 cols (lanes of quad)
#pragma unroll
  for (int m = 1; m < 16; m <<= 1) {
#pragma unroll
    for (int i = 0; i < 4; ++i) s[i] += __shfl_xor(s[i], m, 64);
  }
  if (l16 == 0) {
#pragma unroll
    for (int i = 0; i < 4; ++i) atomicAdd(&s_sum[qbase + quad * 4 + i], s[i]);
  }
}

// ---------------- per-stage: lse -> outer loss accumulator ----------------
__global__ __launch_bounds__(256) void lse_final_kernel(
    const float* __restrict__ s_sum, const float* __restrict__ pos,
    float* __restrict__ acc, int stage) {
  const int t = threadIdx.x;
  const int k = blockIdx.x * 256 + t;
  float v = 10.0f + __logf(s_sum[k]) - pos[k];
#pragma unroll
  for (int m = 1; m < 64; m <<= 1) v += __shfl_xor(v, m, 64);
  __shared__ float red[4];
  if ((t & 63) == 0) red[t >> 6] = v;
  __syncthreads();
  if (t == 0) atomicAdd(&acc[4 + stage], red[0] + red[1] + red[2] + red[3]);
}

// ---------------- per-stage: codebook row norms ----------------
__global__ __launch_bounds__(256) void cbnorm_kernel(
    const float* __restrict__ cb, float* __restrict__ cbn) {
  const int wave = threadIdx.x >> 6, lane = threadIdx.x & 63;
  const int e = blockIdx.x * 4 + wave;
  float4 v = ((const float4*)(cb + (size_t)e * DIM))[lane];
  float ss = v.x * v.x + v.y * v.y + v.z * v.z + v.w * v.w;
#pragma unroll
  for (int m = 1; m < 64; m <<= 1) ss += __shfl_xor(ss, m, 64);
  if (lane == 0) cbn[e] = ss;
}

// ---------------- per-stage: fp32 cdist + argmin (tile 64 rows x 256 entries) ----------------
__global__ __launch_bounds__(256) void argmin_kernel(
    const float* __restrict__ resid, const float* __restrict__ cb,
    const float* __restrict__ cbn, const float* __restrict__ rnorm,
    int* __restrict__ idx_out) {
  __shared__ float cbT[32][NE];   // [k][e]
  __shared__ float rT[32][64];    // [k][r]
  const int tid = threadIdx.x;
  const int rbase = blockIdx.x * 64;
  float acc[8][8];
#pragma unroll
  for (int i = 0; i < 8; ++i)
#pragma unroll
    for (int j = 0; j < 8; ++j) acc[i][j] = 0.0f;
  const int r0  = (tid >> 5) << 3;
  const int e0  = (tid & 31) << 3;
  const int klo = (tid & 3) * 8;
  for (int kc = 0; kc < DIM; kc += 32) {
    __syncthreads();
#pragma unroll
    for (int j = 0; j < 4; ++j) {
      const int e = (tid >> 2) + 64 * j;
      const float4* src = (const float4*)(cb + (size_t)e * DIM + kc + klo);
      float4 v0 = src[0], v1 = src[1];
      cbT[klo + 0][e] = v0.x; cbT[klo + 1][e] = v0.y;
      cbT[klo + 2][e] = v0.z; cbT[klo + 3][e] = v0.w;
      cbT[klo + 4][e] = v1.x; cbT[klo + 5][e] = v1.y;
      cbT[klo + 6][e] = v1.z; cbT[klo + 7][e] = v1.w;
    }
    {
      const int r = tid >> 2;
      const float4* src = (const float4*)(resid + (size_t)(rbase + r) * DIM + kc + klo);
      float4 v0 = src[0], v1 = src[1];
      rT[klo + 0][r] = v0.x; rT[klo + 1][r] = v0.y;
      rT[klo + 2][r] = v0.z; rT[klo + 3][r] = v0.w;
      rT[klo + 4][r] = v1.x; rT[klo + 5][r] = v1.y;
      rT[klo + 6][r] = v1.z; rT[klo + 7][r] = v1.w;
    }
    __syncthreads();
#pragma unroll 4
    for (int k = 0; k < 32; ++k) {
      float rv[8], cv[8];
      *(float4*)&rv[0] = *(const float4*)&rT[k][r0];
      *(float4*)&rv[4] = *(const float4*)&rT[k][r0 + 4];
      *(float4*)&cv[0] = *(const float4*)&cbT[k][e0];
      *(float4*)&cv[4] = *(const float4*)&cbT[k][e0 + 4];
#pragma unroll
      for (int i = 0; i < 8; ++i)
#pragma unroll
        for (int j = 0; j < 8; ++j) acc[i][j] = fmaf(rv[i], cv[j], acc[i][j]);
    }
  }
  float best[8]; int bidx[8];
#pragma unroll
  for (int i = 0; i < 8; ++i) {
    const float rn = rnorm[rbase + r0 + i];
    best[i] = 3.4e38f; bidx[i] = 0;
#pragma unroll
    for (int j = 0; j < 8; ++j) {
      const float sc = (rn - 2.0f * acc[i][j]) + cbn[e0 + j];
      if (sc < best[i]) { best[i] = sc; bidx[i] = e0 + j; }
    }
  }
  // reduce over the 32 threads (same tid>>5) holding this row group
#pragma unroll
  for (int m = 16; m >= 1; m >>= 1) {
#pragma unroll
    for (int i = 0; i < 8; ++i) {
      const float vo = __shfl_xor(best[i], m, 64);
      const int   io = __shfl_xor(bidx[i], m, 64);
      if (vo < best[i] || (vo == best[i] && io < bidx[i])) { best[i] = vo; bidx[i] = io; }
    }
  }
  if ((tid & 31) == 0) {
#pragma unroll
    for (int i = 0; i < 8; ++i) idx_out[rbase + r0 + i] = bidx[i];
  }
}

// ---------------- per-stage: residual update, x_q accumulate, MSE, idx out ----------------
__global__ __launch_bounds__(256) void update_kernel(
    float* __restrict__ resid, const float* __restrict__ cb,
    const int* __restrict__ idx, float* __restrict__ xq,
    float* __restrict__ idxf, float* __restrict__ acc, int stage) {
  const int wave = threadIdx.x >> 6, lane = threadIdx.x & 63;
  const int row = blockIdx.x * 4 + wave;
  const int e = idx[row];
  float4 r = ((const float4*)(resid + (size_t)row * DIM))[lane];
  float4 q = ((const float4*)(cb + (size_t)e * DIM))[lane];
  const float dx = q.x - r.x, dy = q.y - r.y, dz = q.z - r.z, dw = q.w - r.w;
  float ss = dx * dx + dy * dy + dz * dz + dw * dw;
  float4 nr = {r.x - q.x, r.y - q.y, r.z - q.z, r.w - q.w};
  ((float4*)(resid + (size_t)row * DIM))[lane] = nr;
  float4* xp = (float4*)(xq + (size_t)row * DIM) + lane;
  if (stage == 0) {
    *xp = q;
  } else {
    float4 o = *xp;
    o.x += q.x; o.y += q.y; o.z += q.z; o.w += q.w;
    *xp = o;
  }
#pragma unroll
  for (int m = 1; m < 64; m <<= 1) ss += __shfl_xor(ss, m, 64);
  if (lane == 0) {
    atomicAdd(&acc[0], ss);
    idxf[(size_t)row * NQ + stage] = (float)e;
  }
}

// ---------------- finalize scalar outputs ----------------
__global__ void finalize_kernel(const float* __restrict__ acc, float* __restrict__ out) {
  const int t = threadIdx.x;
  if (t == 0) out[ND] = acc[0] * (1.25f / (4.0f * (float)ND));
  if (t < 4) out[ND + 1 + t] = acc[4 + t] * (1.0f / (float)KP);
}

extern "C" void kernel_launch(void* const* d_in, const int* in_sizes, int n_in,
                              void* d_out, int out_size, void* d_ws, size_t ws_size,
                              hipStream_t stream) {
  const float* x         = (const float*)d_in[0];
  const float* codebooks = (const float*)d_in[1];
  const int*   i1        = (const int*)d_in[2];
  const int*   i2        = (const int*)d_in[3];
  float* out = (float*)d_out;
  float* out_xq   = out;                 // [N, D]
  float* out_idxf = out + ND + 1 + NQ;   // [N, NQ] as float

  char* w = (char*)d_ws;
  float*          resid = (float*)w;          w += (size_t)N_ROWS * DIM * 4;
  unsigned short* Xn    = (unsigned short*)w; w += (size_t)N_ROWS * DIM * 2;
  float*          rnorm = (float*)w;          w += (size_t)N_ROWS * 4;
  unsigned short* Qg    = (unsigned short*)w; w += (size_t)KP * DIM * 2;
  float*          pos   = (float*)w;          w += (size_t)KP * 4;
  float*          ssum  = (float*)w;          w += (size_t)KP * 4;
  float*          cbn   = (float*)w;          w += (size_t)NE * 4;
  int*            idxs  = (int*)w;            w += (size_t)N_ROWS * 4;
  float*          acc   = (float*)w;          w += 32;  // [0]=sumsq, [4..7]=outer sums

  copy_kernel<<<8192, 256, 0, stream>>>(x, resid);
  hipMemsetAsync(acc, 0, 32, stream);
  for (int q = 0; q < NQ; ++q) {
    const float* cb = codebooks + (size_t)q * NE * DIM;
    normalize_kernel<<<8192, 256, 0, stream>>>(resid, Xn, rnorm);
    gather_pos_kernel<<<1024, 256, 0, stream>>>(Xn, i1, i2, Qg, pos);
    hipMemsetAsync(ssum, 0, KP * 4, stream);
    sim_lse_kernel<<<dim3(64, 16), 256, 0, stream>>>(Qg, Xn, ssum);
    lse_final_kernel<<<16, 256, 0, stream>>>(ssum, pos, acc, q);
    cbnorm_kernel<<<64, 256, 0, stream>>>(cb, cbn);
    argmin_kernel<<<512, 256, 0, stream>>>(resid, cb, cbn, rnorm, idxs);
    update_kernel<<<8192, 256, 0, stream>>>(resid, cb, idxs, out_xq, out_idxf, acc, q);
  }
  finalize_kernel<<<1, 64, 0, stream>>>(acc, out);
}

// Round 3
// 1275.360 us; speedup vs baseline: 3.0787x; 3.0787x over previous
//
#include <hip/hip_runtime.h>

#define N_ROWS 32768
#define DIM    256
#define NE     256
#define KP     4096
#define NQ     4
#define ND     8388608   // N_ROWS*DIM
#define SIM_G  32        // 16-row B groups per sim block

typedef short short8 __attribute__((ext_vector_type(8)));
typedef float f32x4  __attribute__((ext_vector_type(4)));
typedef const __attribute__((address_space(1))) unsigned int glb_u32;
typedef __attribute__((address_space(3))) unsigned int lds_u32;

__device__ inline float bf2f(unsigned short u) {
  return __uint_as_float(((unsigned)u) << 16);
}
__device__ inline unsigned short f2bf(float f) {
  unsigned u = __float_as_uint(f);
  u += 0x7fffu + ((u >> 16) & 1u);
  return (unsigned short)(u >> 16);
}

// ---------------- stage 0 prep: resid = x, Xn = bf16 normalize(x), rnorm ----------------
__global__ __launch_bounds__(256) void prep0_kernel(
    const float* __restrict__ x, float* __restrict__ resid,
    unsigned short* __restrict__ Xn, float* __restrict__ rnorm) {
  const int wave = threadIdx.x >> 6, lane = threadIdx.x & 63;
  const int row = blockIdx.x * 4 + wave;
  float4 v = ((const float4*)(x + (size_t)row * DIM))[lane];
  ((float4*)(resid + (size_t)row * DIM))[lane] = v;
  float ss = v.x * v.x + v.y * v.y + v.z * v.z + v.w * v.w;
#pragma unroll
  for (int m = 1; m < 64; m <<= 1) ss += __shfl_xor(ss, m, 64);
  if (lane == 0) rnorm[row] = ss;
  const float sc = rsqrtf(ss + 1e-12f);
  ushort4 o;
  o.x = f2bf(v.x * sc); o.y = f2bf(v.y * sc);
  o.z = f2bf(v.z * sc); o.w = f2bf(v.w * sc);
  ((ushort4*)(Xn + (size_t)row * DIM))[lane] = o;
}

// ---------------- all codebook row norms (NQ*NE rows), once ----------------
__global__ __launch_bounds__(256) void cbnorm_kernel(
    const float* __restrict__ cb, float* __restrict__ cbn) {
  const int wave = threadIdx.x >> 6, lane = threadIdx.x & 63;
  const int e = blockIdx.x * 4 + wave;  // 0..NQ*NE-1
  float4 v = ((const float4*)(cb + (size_t)e * DIM))[lane];
  float ss = v.x * v.x + v.y * v.y + v.z * v.z + v.w * v.w;
#pragma unroll
  for (int m = 1; m < 64; m <<= 1) ss += __shfl_xor(ss, m, 64);
  if (lane == 0) cbn[e] = ss;
}

// ---------------- per-stage: gather xn[i1] + pos ----------------
__global__ __launch_bounds__(256) void gather_pos_kernel(
    const unsigned short* __restrict__ Xn, const int* __restrict__ i1,
    const int* __restrict__ i2, unsigned short* __restrict__ Qg,
    float* __restrict__ pos) {
  const int wave = threadIdx.x >> 6, lane = threadIdx.x & 63;
  const int k = blockIdx.x * 4 + wave;
  const int a = i1[k], b = i2[k];
  ushort4 va = ((const ushort4*)(Xn + (size_t)a * DIM))[lane];
  ushort4 vb = ((const ushort4*)(Xn + (size_t)b * DIM))[lane];
  ((ushort4*)(Qg + (size_t)k * DIM))[lane] = va;
  float d = bf2f(va.x) * bf2f(vb.x) + bf2f(va.y) * bf2f(vb.y) +
            bf2f(va.z) * bf2f(vb.z) + bf2f(va.w) * bf2f(vb.w);
#pragma unroll
  for (int m = 1; m < 64; m <<= 1) d += __shfl_xor(d, m, 64);
  if (lane == 0) pos[k] = d * 10.0f;  // /TEMP
}

// ---------------- per-stage: sim GEMM (MFMA-dense) + sum(exp(logit-10)) ----------------
// grid (16 qtiles of 256, 64 n-chunks of 512 rows), block 256 = 4 waves.
// Each wave holds 4 A-tiles (64 queries) in regs. 16-row B tile staged to LDS
// with global_load_lds width=16, m97-proven two-barrier single-buffer loop.
__device__ __forceinline__ void stage_b(const unsigned short* src,
                                        unsigned short* dst,
                                        int wave, int lane) {
  const unsigned short* g0 = src + wave * 512 + lane * 8;  // 16B per lane
  unsigned short* l0 = dst + wave * 512;                   // wave-uniform base
  __builtin_amdgcn_global_load_lds((glb_u32*)g0, (lds_u32*)l0, 16, 0, 0);
  __builtin_amdgcn_global_load_lds((glb_u32*)(g0 + 2048), (lds_u32*)(l0 + 2048), 16, 0, 0);
}

__global__ __launch_bounds__(256, 2) void sim_lse_kernel(
    const unsigned short* __restrict__ Qg, const unsigned short* __restrict__ Xn,
    float* __restrict__ s_sum) {
  __shared__ __align__(16) unsigned short Bt[16 * DIM];  // 8KB, single buffer
  const int tid  = threadIdx.x;
  const int lane = tid & 63;
  const int wave = tid >> 6;
  const int quad = lane >> 4;
  const int l16  = lane & 15;
  const int qbase = blockIdx.x * 256 + wave * 64;
  const int nb0 = blockIdx.y * (SIM_G * 16);

  short8 a[4][8];
#pragma unroll
  for (int t = 0; t < 4; ++t) {
    const short8* arow =
        (const short8*)(Qg + (size_t)(qbase + t * 16 + l16) * DIM + quad * 8);
#pragma unroll
    for (int f = 0; f < 8; ++f) a[t][f] = arow[f * 4];
  }
  float s[4][4] = {};
  const float C1 = 14.4269504088896341f;  // 10*log2(e); exp(10d-10)=exp2(d*C1-C1)

  for (int g = 0; g < SIM_G; ++g) {
    __syncthreads();  // all waves done reading Bt (previous group)
    stage_b(Xn + (size_t)(nb0 + g * 16) * DIM, Bt, wave, lane);
    __syncthreads();  // staging landed (compiler drains vmcnt before s_barrier)
    f32x4 acc[4] = {{0.f, 0.f, 0.f, 0.f}, {0.f, 0.f, 0.f, 0.f},
                    {0.f, 0.f, 0.f, 0.f}, {0.f, 0.f, 0.f, 0.f}};
#pragma unroll
    for (int f = 0; f < 8; ++f) {
      short8 b = *(const short8*)(Bt + l16 * DIM + f * 32 + quad * 8);
#pragma unroll
      for (int t = 0; t < 4; ++t)
        acc[t] = __builtin_amdgcn_mfma_f32_16x16x32_bf16(a[t][f], b, acc[t], 0, 0, 0);
    }
#pragma unroll
    for (int t = 0; t < 4; ++t)
#pragma unroll
      for (int i = 0; i < 4; ++i)
        s[t][i] += exp2f(fmaf(acc[t][i], C1, -C1));
  }
  // C layout: col(n) = l16, row(query) = quad*4+i. Reduce over the 16 cols.
#pragma unroll
  for (int m = 1; m < 16; m <<= 1)
#pragma unroll
    for (int t = 0; t < 4; ++t)
#pragma unroll
      for (int i = 0; i < 4; ++i) s[t][i] += __shfl_xor(s[t][i], m, 64);
  if (l16 == 0) {
#pragma unroll
    for (int t = 0; t < 4; ++t)
#pragma unroll
      for (int i = 0; i < 4; ++i)
        atomicAdd(&s_sum[qbase + t * 16 + quad * 4 + i], s[t][i]);
  }
}

// ---------------- per-stage: lse -> outer loss accumulator ----------------
__global__ __launch_bounds__(256) void lse_final_kernel(
    const float* __restrict__ s_sum, const float* __restrict__ pos,
    float* __restrict__ acc, int stage) {
  const int t = threadIdx.x;
  const int k = blockIdx.x * 256 + t;
  float v = 10.0f + __logf(s_sum[k]) - pos[k];
#pragma unroll
  for (int m = 1; m < 64; m <<= 1) v += __shfl_xor(v, m, 64);
  __shared__ float red[4];
  if ((t & 63) == 0) red[t >> 6] = v;
  __syncthreads();
  if (t == 0) atomicAdd(&acc[4 + stage], red[0] + red[1] + red[2] + red[3]);
}

// ---------------- per-stage: fp32 cdist + argmin (64 rows x 256 entries/block) ----------------
__global__ __launch_bounds__(256) void argmin_kernel(
    const float* __restrict__ resid, const float* __restrict__ cb,
    const float* __restrict__ cbn, const float* __restrict__ rnorm,
    int* __restrict__ idx_out) {
  __shared__ float cbT[32][NE];   // [k][e]
  __shared__ float rT[32][64];    // [k][r]
  const int tid = threadIdx.x;
  const int rbase = blockIdx.x * 64;
  const int r0 = (tid >> 5) << 3;
  const int elane = tid & 31;
  const int klo = (tid & 3) * 8;
  float acc[8][8];
#pragma unroll
  for (int i = 0; i < 8; ++i)
#pragma unroll
    for (int j = 0; j < 8; ++j) acc[i][j] = 0.0f;
  for (int kc = 0; kc < DIM; kc += 32) {
    __syncthreads();
#pragma unroll
    for (int j = 0; j < 4; ++j) {
      const int e = (tid >> 2) + 64 * j;
      const float4* src = (const float4*)(cb + (size_t)e * DIM + kc + klo);
      float4 v0 = src[0], v1 = src[1];
      cbT[klo + 0][e] = v0.x; cbT[klo + 1][e] = v0.y;
      cbT[klo + 2][e] = v0.z; cbT[klo + 3][e] = v0.w;
      cbT[klo + 4][e] = v1.x; cbT[klo + 5][e] = v1.y;
      cbT[klo + 6][e] = v1.z; cbT[klo + 7][e] = v1.w;
    }
    {
      const int r = tid >> 2;
      const float4* src = (const float4*)(resid + (size_t)(rbase + r) * DIM + kc + klo);
      float4 v0 = src[0], v1 = src[1];
      rT[klo + 0][r] = v0.x; rT[klo + 1][r] = v0.y;
      rT[klo + 2][r] = v0.z; rT[klo + 3][r] = v0.w;
      rT[klo + 4][r] = v1.x; rT[klo + 5][r] = v1.y;
      rT[klo + 6][r] = v1.z; rT[klo + 7][r] = v1.w;
    }
    __syncthreads();
#pragma unroll 4
    for (int k = 0; k < 32; ++k) {
      float rv[8], cv[8];
      *(float4*)&rv[0] = *(const float4*)&rT[k][r0];
      *(float4*)&rv[4] = *(const float4*)&rT[k][r0 + 4];
#pragma unroll
      for (int j = 0; j < 8; ++j) cv[j] = cbT[k][elane + 32 * j];
#pragma unroll
      for (int i = 0; i < 8; ++i)
#pragma unroll
        for (int j = 0; j < 8; ++j) acc[i][j] = fmaf(rv[i], cv[j], acc[i][j]);
    }
  }
  float best[8]; int bidx[8];
#pragma unroll
  for (int i = 0; i < 8; ++i) {
    const float rn = rnorm[rbase + r0 + i];
    best[i] = 3.4e38f; bidx[i] = 0;
#pragma unroll
    for (int j = 0; j < 8; ++j) {
      const int e = elane + 32 * j;
      const float sc = (rn - 2.0f * acc[i][j]) + cbn[e];
      if (sc < best[i]) { best[i] = sc; bidx[i] = e; }
    }
  }
#pragma unroll
  for (int m = 16; m >= 1; m >>= 1) {
#pragma unroll
    for (int i = 0; i < 8; ++i) {
      const float vo = __shfl_xor(best[i], m, 64);
      const int   io = __shfl_xor(bidx[i], m, 64);
      if (vo < best[i] || (vo == best[i] && io < bidx[i])) { best[i] = vo; bidx[i] = io; }
    }
  }
  if ((tid & 31) == 0) {
#pragma unroll
    for (int i = 0; i < 8; ++i) idx_out[rbase + r0 + i] = bidx[i];
  }
}

// ---------------- per-stage: residual update + fused next-stage normalize ----------------
__global__ __launch_bounds__(256) void update_kernel(
    float* __restrict__ resid, const float* __restrict__ cb,
    const int* __restrict__ idx, float* __restrict__ xq,
    float* __restrict__ idxf, float* __restrict__ acc,
    unsigned short* __restrict__ Xn, float* __restrict__ rnorm, int stage) {
  const int wave = threadIdx.x >> 6, lane = threadIdx.x & 63;
  const int row = blockIdx.x * 4 + wave;
  const int e = idx[row];
  float4 r = ((const float4*)(resid + (size_t)row * DIM))[lane];
  float4 q = ((const float4*)(cb + (size_t)e * DIM))[lane];
  float4 nr = {r.x - q.x, r.y - q.y, r.z - q.z, r.w - q.w};
  float ss = nr.x * nr.x + nr.y * nr.y + nr.z * nr.z + nr.w * nr.w;
  float4* xp = (float4*)(xq + (size_t)row * DIM) + lane;
  if (stage == 0) {
    *xp = q;
  } else {
    float4 o = *xp;
    o.x += q.x; o.y += q.y; o.z += q.z; o.w += q.w;
    *xp = o;
  }
#pragma unroll
  for (int m = 1; m < 64; m <<= 1) ss += __shfl_xor(ss, m, 64);
  if (stage < 3) {
    ((float4*)(resid + (size_t)row * DIM))[lane] = nr;
    const float sc = rsqrtf(ss + 1e-12f);
    ushort4 o;
    o.x = f2bf(nr.x * sc); o.y = f2bf(nr.y * sc);
    o.z = f2bf(nr.z * sc); o.w = f2bf(nr.w * sc);
    ((ushort4*)(Xn + (size_t)row * DIM))[lane] = o;
    if (lane == 0) rnorm[row] = ss;
  }
  if (lane == 0) idxf[(size_t)row * NQ + stage] = (float)e;
  __shared__ float red[4];
  if (lane == 0) red[wave] = ss;
  __syncthreads();
  if (threadIdx.x == 0) atomicAdd(&acc[0], red[0] + red[1] + red[2] + red[3]);
}

// ---------------- finalize scalar outputs ----------------
__global__ void finalize_kernel(const float* __restrict__ acc, float* __restrict__ out) {
  const int t = threadIdx.x;
  if (t == 0) out[ND] = acc[0] * (1.25f / (4.0f * (float)ND));
  if (t < 4) out[ND + 1 + t] = acc[4 + t] * (1.0f / (float)KP);
}

extern "C" void kernel_launch(void* const* d_in, const int* in_sizes, int n_in,
                              void* d_out, int out_size, void* d_ws, size_t ws_size,
                              hipStream_t stream) {
  const float* x         = (const float*)d_in[0];
  const float* codebooks = (const float*)d_in[1];
  const int*   i1        = (const int*)d_in[2];
  const int*   i2        = (const int*)d_in[3];
  float* out = (float*)d_out;
  float* out_xq   = out;                 // [N, D]
  float* out_idxf = out + ND + 1 + NQ;   // [N, NQ] as float

  char* w = (char*)d_ws;
  float*          resid = (float*)w;          w += (size_t)N_ROWS * DIM * 4;
  unsigned short* Xn    = (unsigned short*)w; w += (size_t)N_ROWS * DIM * 2;
  float*          rnorm = (float*)w;          w += (size_t)N_ROWS * 4;
  unsigned short* Qg    = (unsigned short*)w; w += (size_t)KP * DIM * 2;
  float*          pos   = (float*)w;          w += (size_t)KP * 4;
  float*          ssum  = (float*)w;          w += (size_t)KP * 4;
  float*          cbn   = (float*)w;          w += (size_t)NQ * NE * 4;
  int*            idxs  = (int*)w;            w += (size_t)N_ROWS * 4;
  float*          acc   = (float*)w;          w += 32;  // [0]=sumsq, [4..7]=outer sums

  prep0_kernel<<<8192, 256, 0, stream>>>(x, resid, Xn, rnorm);
  cbnorm_kernel<<<256, 256, 0, stream>>>(codebooks, cbn);
  hipMemsetAsync(acc, 0, 32, stream);
  for (int q = 0; q < NQ; ++q) {
    const float* cb = codebooks + (size_t)q * NE * DIM;
    gather_pos_kernel<<<1024, 256, 0, stream>>>(Xn, i1, i2, Qg, pos);
    hipMemsetAsync(ssum, 0, KP * 4, stream);
    sim_lse_kernel<<<dim3(16, 64), 256, 0, stream>>>(Qg, Xn, ssum);
    lse_final_kernel<<<16, 256, 0, stream>>>(ssum, pos, acc, q);
    argmin_kernel<<<512, 256, 0, stream>>>(resid, cb, cbn + q * NE, rnorm, idxs);
    update_kernel<<<8192, 256, 0, stream>>>(resid, cb, idxs, out_xq, out_idxf, acc,
                                            Xn, rnorm, q);
  }
  finalize_kernel<<<1, 64, 0, stream>>>(acc, out);
}

// Round 4
// 772.165 us; speedup vs baseline: 5.0850x; 1.6517x over previous
//
#include <hip/hip_runtime.h>

#define N_ROWS 32768
#define DIM    256
#define NE     256
#define KP     4096
#define NQ     4
#define ND     8388608   // N_ROWS*DIM

typedef short short8 __attribute__((ext_vector_type(8)));
typedef float f32x4  __attribute__((ext_vector_type(4)));
typedef const __attribute__((address_space(1))) unsigned int glb_u32;
typedef __attribute__((address_space(3))) unsigned int lds_u32;

__device__ inline float bf2f(unsigned short u) {
  return __uint_as_float(((unsigned)u) << 16);
}
__device__ inline unsigned short f2bf(float f) {
  unsigned u = __float_as_uint(f);
  u += 0x7fffu + ((u >> 16) & 1u);
  return (unsigned short)(u >> 16);
}

// ---------------- stage 0 prep: resid = x, Xn = bf16 normalize(x), rnorm ----------------
__global__ __launch_bounds__(256) void prep0_kernel(
    const float* __restrict__ x, float* __restrict__ resid,
    unsigned short* __restrict__ Xn, float* __restrict__ rnorm) {
  const int wave = threadIdx.x >> 6, lane = threadIdx.x & 63;
  const int row = blockIdx.x * 4 + wave;
  float4 v = ((const float4*)(x + (size_t)row * DIM))[lane];
  ((float4*)(resid + (size_t)row * DIM))[lane] = v;
  float ss = v.x * v.x + v.y * v.y + v.z * v.z + v.w * v.w;
#pragma unroll
  for (int m = 1; m < 64; m <<= 1) ss += __shfl_xor(ss, m, 64);
  if (lane == 0) rnorm[row] = ss;
  const float sc = rsqrtf(ss + 1e-12f);
  ushort4 o;
  o.x = f2bf(v.x * sc); o.y = f2bf(v.y * sc);
  o.z = f2bf(v.z * sc); o.w = f2bf(v.w * sc);
  ((ushort4*)(Xn + (size_t)row * DIM))[lane] = o;
}

// ---------------- all codebook row norms (NQ*NE rows), once ----------------
__global__ __launch_bounds__(256) void cbnorm_kernel(
    const float* __restrict__ cb, float* __restrict__ cbn) {
  const int wave = threadIdx.x >> 6, lane = threadIdx.x & 63;
  const int e = blockIdx.x * 4 + wave;  // 0..NQ*NE-1
  float4 v = ((const float4*)(cb + (size_t)e * DIM))[lane];
  float ss = v.x * v.x + v.y * v.y + v.z * v.z + v.w * v.w;
#pragma unroll
  for (int m = 1; m < 64; m <<= 1) ss += __shfl_xor(ss, m, 64);
  if (lane == 0) cbn[e] = ss;
}

// ---------------- per-stage: gather xn[i1] + pos; also zero ssum ----------------
__global__ __launch_bounds__(256) void gather_pos_kernel(
    const unsigned short* __restrict__ Xn, const int* __restrict__ i1,
    const int* __restrict__ i2, unsigned short* __restrict__ Qg,
    float* __restrict__ pos, float* __restrict__ ssum) {
  if (blockIdx.x < 16) ssum[blockIdx.x * 256 + threadIdx.x] = 0.0f;
  const int wave = threadIdx.x >> 6, lane = threadIdx.x & 63;
  const int k = blockIdx.x * 4 + wave;
  const int a = i1[k], b = i2[k];
  ushort4 va = ((const ushort4*)(Xn + (size_t)a * DIM))[lane];
  ushort4 vb = ((const ushort4*)(Xn + (size_t)b * DIM))[lane];
  ((ushort4*)(Qg + (size_t)k * DIM))[lane] = va;
  float d = bf2f(va.x) * bf2f(vb.x) + bf2f(va.y) * bf2f(vb.y) +
            bf2f(va.z) * bf2f(vb.z) + bf2f(va.w) * bf2f(vb.w);
#pragma unroll
  for (int m = 1; m < 64; m <<= 1) d += __shfl_xor(d, m, 64);
  if (lane == 0) pos[k] = d * 10.0f;  // /TEMP
}

// ---------------- per-stage: sim GEMM (MFMA) + sum(exp(logit-10)) ----------------
// grid (16 qtiles of 256, 64 n-chunks of 512 rows), block 256 = 4 waves.
// 32-row B tile in LDS, XOR-swizzled at 16B-chunk granularity:
// chunk c of row r lives at position c ^ (r&7)  ->  ds_read_b128 conflict-free.
// global_load_lds can't scatter its LDS side (base + lane*16), so the *global*
// source per lane is chosen to be the chunk belonging in that lane's LDS slot.
__device__ __forceinline__ void stage_b32(const unsigned short* __restrict__ src,
                                          unsigned short* dst, int wave, int lane) {
#pragma unroll
  for (int i = 0; i < 4; ++i) {
    const int p = wave * 64 + i * 256 + lane;   // LDS 16B-chunk index [0,1024)
    const int r = p >> 5;                       // row 0..31
    const int c = (p & 31) ^ (r & 7);           // global chunk for this slot
    const unsigned short* g = src + r * DIM + c * 8;        // per-lane global
    unsigned short* l = dst + (wave * 64 + i * 256) * 8;    // wave-uniform base
    __builtin_amdgcn_global_load_lds((glb_u32*)g, (lds_u32*)l, 16, 0, 0);
  }
}

__global__ __launch_bounds__(256, 2) void sim_lse_kernel(
    const unsigned short* __restrict__ Qg, const unsigned short* __restrict__ Xn,
    float* __restrict__ s_sum) {
  __shared__ __align__(16) unsigned short Bt[32 * DIM];  // 16KB, single buffer
  const int tid  = threadIdx.x;
  const int lane = tid & 63;
  const int wave = tid >> 6;
  const int quad = lane >> 4;
  const int l16  = lane & 15;
  const int qbase = blockIdx.x * 256 + wave * 64;
  const int nb0 = blockIdx.y * 512;

  short8 a[4][8];
#pragma unroll
  for (int t = 0; t < 4; ++t) {
    const short8* arow =
        (const short8*)(Qg + (size_t)(qbase + t * 16 + l16) * DIM + quad * 8);
#pragma unroll
    for (int f = 0; f < 8; ++f) a[t][f] = arow[f * 4];
  }
  float s[4][4] = {};
  const float C1 = 14.4269504088896341f;  // 10*log2(e); exp(10d-10)=exp2(d*C1-C1)
  const int sw = l16 & 7;

  for (int g = 0; g < 16; ++g) {
    __syncthreads();  // all waves done reading Bt (previous tile)
    stage_b32(Xn + (size_t)(nb0 + g * 32) * DIM, Bt, wave, lane);
    __syncthreads();  // staging landed (vmcnt drained before barrier)
#pragma unroll
    for (int u = 0; u < 2; ++u) {
      const unsigned short* bt = Bt + (u * 16 + l16) * DIM;  // (row&7) == l16&7
      f32x4 acc[4] = {{0.f, 0.f, 0.f, 0.f}, {0.f, 0.f, 0.f, 0.f},
                      {0.f, 0.f, 0.f, 0.f}, {0.f, 0.f, 0.f, 0.f}};
#pragma unroll
      for (int f = 0; f < 8; ++f) {
        short8 b = *(const short8*)(bt + ((((f << 2) + quad) ^ sw) << 3));
#pragma unroll
        for (int t = 0; t < 4; ++t)
          acc[t] = __builtin_amdgcn_mfma_f32_16x16x32_bf16(a[t][f], b, acc[t], 0, 0, 0);
      }
#pragma unroll
      for (int t = 0; t < 4; ++t)
#pragma unroll
        for (int i = 0; i < 4; ++i)
          s[t][i] += exp2f(fmaf(acc[t][i], C1, -C1));
    }
  }
  // C layout: col(n) = l16, row(query) = quad*4+i. Reduce over the 16 cols.
#pragma unroll
  for (int m = 1; m < 16; m <<= 1)
#pragma unroll
    for (int t = 0; t < 4; ++t)
#pragma unroll
      for (int i = 0; i < 4; ++i) s[t][i] += __shfl_xor(s[t][i], m, 64);
  if (l16 == 0) {
#pragma unroll
    for (int t = 0; t < 4; ++t)
#pragma unroll
      for (int i = 0; i < 4; ++i)
        atomicAdd(&s_sum[qbase + t * 16 + quad * 4 + i], s[t][i]);
  }
}

// ---------------- per-stage: lse -> outer loss accumulator ----------------
__global__ __launch_bounds__(256) void lse_final_kernel(
    const float* __restrict__ s_sum, const float* __restrict__ pos,
    float* __restrict__ acc, int stage) {
  const int t = threadIdx.x;
  const int k = blockIdx.x * 256 + t;
  float v = 10.0f + __logf(s_sum[k]) - pos[k];
#pragma unroll
  for (int m = 1; m < 64; m <<= 1) v += __shfl_xor(v, m, 64);
  __shared__ float red[4];
  if ((t & 63) == 0) red[t >> 6] = v;
  __syncthreads();
  if (t == 0) atomicAdd(&acc[4 + stage], red[0] + red[1] + red[2] + red[3]);
}

// ---------------- per-stage: fused fp32 argmin + residual update ----------------
// Block owns rows [rbase, rbase+64): argmin over 256 entries, then in-block
// barrier, then update resid/xq/Xn/rnorm/idxf/MSE for those rows.
__global__ __launch_bounds__(256) void argmin_update_kernel(
    float* __restrict__ resid, const float* __restrict__ cb,
    const float* __restrict__ cbn, const float* __restrict__ rnorm,
    float* __restrict__ xq, float* __restrict__ idxf, float* __restrict__ acc,
    unsigned short* __restrict__ Xn, int stage) {
  __shared__ float cbT[32][NE];   // [k][e]
  __shared__ float rT[32][64];    // [k][r]
  __shared__ int   sIdx[64];
  __shared__ float sred[4];
  const int tid = threadIdx.x;
  const int rbase = blockIdx.x * 64;
  const int r0 = (tid >> 5) << 3;
  const int elane = tid & 31;
  const int klo = (tid & 3) * 8;
  float accm[8][8];
#pragma unroll
  for (int i = 0; i < 8; ++i)
#pragma unroll
    for (int j = 0; j < 8; ++j) accm[i][j] = 0.0f;
  for (int kc = 0; kc < DIM; kc += 32) {
    __syncthreads();
#pragma unroll
    for (int j = 0; j < 4; ++j) {
      const int e = (tid >> 2) + 64 * j;
      const float4* src = (const float4*)(cb + (size_t)e * DIM + kc + klo);
      float4 v0 = src[0], v1 = src[1];
      cbT[klo + 0][e] = v0.x; cbT[klo + 1][e] = v0.y;
      cbT[klo + 2][e] = v0.z; cbT[klo + 3][e] = v0.w;
      cbT[klo + 4][e] = v1.x; cbT[klo + 5][e] = v1.y;
      cbT[klo + 6][e] = v1.z; cbT[klo + 7][e] = v1.w;
    }
    {
      const int r = tid >> 2;
      const float4* src = (const float4*)(resid + (size_t)(rbase + r) * DIM + kc + klo);
      float4 v0 = src[0], v1 = src[1];
      rT[klo + 0][r] = v0.x; rT[klo + 1][r] = v0.y;
      rT[klo + 2][r] = v0.z; rT[klo + 3][r] = v0.w;
      rT[klo + 4][r] = v1.x; rT[klo + 5][r] = v1.y;
      rT[klo + 6][r] = v1.z; rT[klo + 7][r] = v1.w;
    }
    __syncthreads();
#pragma unroll 4
    for (int k = 0; k < 32; ++k) {
      float rv[8], cv[8];
      *(float4*)&rv[0] = *(const float4*)&rT[k][r0];
      *(float4*)&rv[4] = *(const float4*)&rT[k][r0 + 4];
#pragma unroll
      for (int j = 0; j < 8; ++j) cv[j] = cbT[k][elane + 32 * j];
#pragma unroll
      for (int i = 0; i < 8; ++i)
#pragma unroll
        for (int j = 0; j < 8; ++j) accm[i][j] = fmaf(rv[i], cv[j], accm[i][j]);
    }
  }
  float best[8]; int bidx[8];
#pragma unroll
  for (int i = 0; i < 8; ++i) {
    const float rn = rnorm[rbase + r0 + i];
    best[i] = 3.4e38f; bidx[i] = 0;
#pragma unroll
    for (int j = 0; j < 8; ++j) {
      const int e = elane + 32 * j;
      const float sc = (rn - 2.0f * accm[i][j]) + cbn[e];
      if (sc < best[i]) { best[i] = sc; bidx[i] = e; }
    }
  }
#pragma unroll
  for (int m = 16; m >= 1; m >>= 1) {
#pragma unroll
    for (int i = 0; i < 8; ++i) {
      const float vo = __shfl_xor(best[i], m, 64);
      const int   io = __shfl_xor(bidx[i], m, 64);
      if (vo < best[i] || (vo == best[i] && io < bidx[i])) { best[i] = vo; bidx[i] = io; }
    }
  }
  if ((tid & 31) == 0) {
#pragma unroll
    for (int i = 0; i < 8; ++i) sIdx[r0 + i] = bidx[i];
  }
  __syncthreads();  // all resid/rnorm reads done; sIdx visible

  // ---- update phase: wave per row, 16 passes ----
  const int wave = tid >> 6, lane = tid & 63;
  float msum = 0.0f;
  for (int i = 0; i < 16; ++i) {
    const int rr = i * 4 + wave;
    const int row = rbase + rr;
    const int e = sIdx[rr];
    float4 r4 = ((const float4*)(resid + (size_t)row * DIM))[lane];
    float4 q4 = ((const float4*)(cb + (size_t)e * DIM))[lane];
    float4 nr = {r4.x - q4.x, r4.y - q4.y, r4.z - q4.z, r4.w - q4.w};
    float ss = nr.x * nr.x + nr.y * nr.y + nr.z * nr.z + nr.w * nr.w;
    float4* xp = (float4*)(xq + (size_t)row * DIM) + lane;
    if (stage == 0) {
      *xp = q4;
    } else {
      float4 o = *xp;
      o.x += q4.x; o.y += q4.y; o.z += q4.z; o.w += q4.w;
      *xp = o;
    }
#pragma unroll
    for (int m = 1; m < 64; m <<= 1) ss += __shfl_xor(ss, m, 64);
    if (stage < 3) {
      ((float4*)(resid + (size_t)row * DIM))[lane] = nr;
      const float sc = rsqrtf(ss + 1e-12f);
      ushort4 o;
      o.x = f2bf(nr.x * sc); o.y = f2bf(nr.y * sc);
      o.z = f2bf(nr.z * sc); o.w = f2bf(nr.w * sc);
      ((ushort4*)(Xn + (size_t)row * DIM))[lane] = o;
      if (lane == 0) ((float*)rnorm)[row] = ss;
    }
    if (lane == 0) {
      idxf[(size_t)row * NQ + stage] = (float)e;
      msum += ss;
    }
  }
  if (lane == 0) sred[wave] = msum;
  __syncthreads();
  if (tid == 0) atomicAdd(&acc[0], sred[0] + sred[1] + sred[2] + sred[3]);
}

// ---------------- finalize scalar outputs ----------------
__global__ void finalize_kernel(const float* __restrict__ acc, float* __restrict__ out) {
  const int t = threadIdx.x;
  if (t == 0) out[ND] = acc[0] * (1.25f / (4.0f * (float)ND));
  if (t < 4) out[ND + 1 + t] = acc[4 + t] * (1.0f / (float)KP);
}

extern "C" void kernel_launch(void* const* d_in, const int* in_sizes, int n_in,
                              void* d_out, int out_size, void* d_ws, size_t ws_size,
                              hipStream_t stream) {
  const float* x         = (const float*)d_in[0];
  const float* codebooks = (const float*)d_in[1];
  const int*   i1        = (const int*)d_in[2];
  const int*   i2        = (const int*)d_in[3];
  float* out = (float*)d_out;
  float* out_xq   = out;                 // [N, D]
  float* out_idxf = out + ND + 1 + NQ;   // [N, NQ] as float

  char* w = (char*)d_ws;
  float*          resid = (float*)w;          w += (size_t)N_ROWS * DIM * 4;
  unsigned short* Xn    = (unsigned short*)w; w += (size_t)N_ROWS * DIM * 2;
  float*          rnorm = (float*)w;          w += (size_t)N_ROWS * 4;
  unsigned short* Qg    = (unsigned short*)w; w += (size_t)KP * DIM * 2;
  float*          pos   = (float*)w;          w += (size_t)KP * 4;
  float*          ssum  = (float*)w;          w += (size_t)KP * 4;
  float*          cbn   = (float*)w;          w += (size_t)NQ * NE * 4;
  float*          acc   = (float*)w;          w += 32;  // [0]=sumsq, [4..7]=outer sums

  prep0_kernel<<<8192, 256, 0, stream>>>(x, resid, Xn, rnorm);
  cbnorm_kernel<<<256, 256, 0, stream>>>(codebooks, cbn);
  hipMemsetAsync(acc, 0, 32, stream);
  for (int q = 0; q < NQ; ++q) {
    const float* cb = codebooks + (size_t)q * NE * DIM;
    gather_pos_kernel<<<1024, 256, 0, stream>>>(Xn, i1, i2, Qg, pos, ssum);
    sim_lse_kernel<<<dim3(16, 64), 256, 0, stream>>>(Qg, Xn, ssum);
    lse_final_kernel<<<16, 256, 0, stream>>>(ssum, pos, acc, q);
    argmin_update_kernel<<<512, 256, 0, stream>>>(resid, cb, cbn + q * NE, rnorm,
                                                  out_xq, out_idxf, acc, Xn, q);
  }
  finalize_kernel<<<1, 64, 0, stream>>>(acc, out);
}

// Round 5
// 727.034 us; speedup vs baseline: 5.4007x; 1.0621x over previous
//
#include <hip/hip_runtime.h>

#define N_ROWS 32768
#define DIM    256
#define NE     256
#define KP     4096
#define NQ     4
#define ND     8388608   // N_ROWS*DIM
#define RESCORE_MARGIN 2e-4f

typedef short short8 __attribute__((ext_vector_type(8)));
typedef float f32x4  __attribute__((ext_vector_type(4)));
typedef const __attribute__((address_space(1))) unsigned int glb_u32;
typedef __attribute__((address_space(3))) unsigned int lds_u32;

__device__ inline float bf2f(unsigned short u) {
  return __uint_as_float(((unsigned)u) << 16);
}
__device__ inline unsigned short f2bf(float f) {
  unsigned u = __float_as_uint(f);
  u += 0x7fffu + ((u >> 16) & 1u);
  return (unsigned short)(u >> 16);
}

// ---------------- stage 0 prep: resid = x, Xn, rnorm, hi/lo split planes ----------------
__global__ __launch_bounds__(256) void prep0_kernel(
    const float* __restrict__ x, float* __restrict__ resid,
    unsigned short* __restrict__ Xn, float* __restrict__ rnorm,
    unsigned short* __restrict__ rH, unsigned short* __restrict__ rL) {
  const int wave = threadIdx.x >> 6, lane = threadIdx.x & 63;
  const int row = blockIdx.x * 4 + wave;
  float4 v = ((const float4*)(x + (size_t)row * DIM))[lane];
  ((float4*)(resid + (size_t)row * DIM))[lane] = v;
  ushort4 h, l;
  h.x = f2bf(v.x); l.x = f2bf(v.x - bf2f(h.x));
  h.y = f2bf(v.y); l.y = f2bf(v.y - bf2f(h.y));
  h.z = f2bf(v.z); l.z = f2bf(v.z - bf2f(h.z));
  h.w = f2bf(v.w); l.w = f2bf(v.w - bf2f(h.w));
  ((ushort4*)(rH + (size_t)row * DIM))[lane] = h;
  ((ushort4*)(rL + (size_t)row * DIM))[lane] = l;
  float ss = v.x * v.x + v.y * v.y + v.z * v.z + v.w * v.w;
#pragma unroll
  for (int m = 1; m < 64; m <<= 1) ss += __shfl_xor(ss, m, 64);
  if (lane == 0) rnorm[row] = ss;
  const float sc = rsqrtf(ss + 1e-12f);
  ushort4 o;
  o.x = f2bf(v.x * sc); o.y = f2bf(v.y * sc);
  o.z = f2bf(v.z * sc); o.w = f2bf(v.w * sc);
  ((ushort4*)(Xn + (size_t)row * DIM))[lane] = o;
}

// ---------------- all codebook row norms (NQ*NE rows), once ----------------
__global__ __launch_bounds__(256) void cbnorm_kernel(
    const float* __restrict__ cb, float* __restrict__ cbn) {
  const int wave = threadIdx.x >> 6, lane = threadIdx.x & 63;
  const int e = blockIdx.x * 4 + wave;  // 0..NQ*NE-1
  float4 v = ((const float4*)(cb + (size_t)e * DIM))[lane];
  float ss = v.x * v.x + v.y * v.y + v.z * v.z + v.w * v.w;
#pragma unroll
  for (int m = 1; m < 64; m <<= 1) ss += __shfl_xor(ss, m, 64);
  if (lane == 0) cbn[e] = ss;
}

// ---------------- codebook hi/lo split (all NQ codebooks), once ----------------
__global__ __launch_bounds__(256) void cbsplit_kernel(
    const float* __restrict__ cb, unsigned short* __restrict__ cbH,
    unsigned short* __restrict__ cbL) {
  const size_t i = (size_t)blockIdx.x * 256 + threadIdx.x;  // 65536 threads
  float4 v = ((const float4*)cb)[i];
  ushort4 h, l;
  h.x = f2bf(v.x); l.x = f2bf(v.x - bf2f(h.x));
  h.y = f2bf(v.y); l.y = f2bf(v.y - bf2f(h.y));
  h.z = f2bf(v.z); l.z = f2bf(v.z - bf2f(h.z));
  h.w = f2bf(v.w); l.w = f2bf(v.w - bf2f(h.w));
  ((ushort4*)cbH)[i] = h;
  ((ushort4*)cbL)[i] = l;
}

// ---------------- per-stage: gather xn[i1] + pos; also zero ssum ----------------
__global__ __launch_bounds__(256) void gather_pos_kernel(
    const unsigned short* __restrict__ Xn, const int* __restrict__ i1,
    const int* __restrict__ i2, unsigned short* __restrict__ Qg,
    float* __restrict__ pos, float* __restrict__ ssum) {
  if (blockIdx.x < 16) ssum[blockIdx.x * 256 + threadIdx.x] = 0.0f;
  const int wave = threadIdx.x >> 6, lane = threadIdx.x & 63;
  const int k = blockIdx.x * 4 + wave;
  const int a = i1[k], b = i2[k];
  ushort4 va = ((const ushort4*)(Xn + (size_t)a * DIM))[lane];
  ushort4 vb = ((const ushort4*)(Xn + (size_t)b * DIM))[lane];
  ((ushort4*)(Qg + (size_t)k * DIM))[lane] = va;
  float d = bf2f(va.x) * bf2f(vb.x) + bf2f(va.y) * bf2f(vb.y) +
            bf2f(va.z) * bf2f(vb.z) + bf2f(va.w) * bf2f(vb.w);
#pragma unroll
  for (int m = 1; m < 64; m <<= 1) d += __shfl_xor(d, m, 64);
  if (lane == 0) pos[k] = d * 10.0f;  // /TEMP
}

// ---------------- per-stage: sim GEMM (MFMA) + sum(exp(logit-10)) ----------------
__device__ __forceinline__ void stage_b32(const unsigned short* __restrict__ src,
                                          unsigned short* dst, int wave, int lane) {
#pragma unroll
  for (int i = 0; i < 4; ++i) {
    const int p = wave * 64 + i * 256 + lane;   // LDS 16B-chunk index [0,1024)
    const int r = p >> 5;                       // row 0..31
    const int c = (p & 31) ^ (r & 7);           // global chunk for this slot
    const unsigned short* g = src + r * DIM + c * 8;        // per-lane global
    unsigned short* l = dst + (wave * 64 + i * 256) * 8;    // wave-uniform base
    __builtin_amdgcn_global_load_lds((glb_u32*)g, (lds_u32*)l, 16, 0, 0);
  }
}

__global__ __launch_bounds__(256, 2) void sim_lse_kernel(
    const unsigned short* __restrict__ Qg, const unsigned short* __restrict__ Xn,
    float* __restrict__ s_sum) {
  __shared__ __align__(16) unsigned short Bt[32 * DIM];  // 16KB, single buffer
  const int tid  = threadIdx.x;
  const int lane = tid & 63;
  const int wave = tid >> 6;
  const int quad = lane >> 4;
  const int l16  = lane & 15;
  const int qbase = blockIdx.x * 256 + wave * 64;
  const int nb0 = blockIdx.y * 512;

  short8 a[4][8];
#pragma unroll
  for (int t = 0; t < 4; ++t) {
    const short8* arow =
        (const short8*)(Qg + (size_t)(qbase + t * 16 + l16) * DIM + quad * 8);
#pragma unroll
    for (int f = 0; f < 8; ++f) a[t][f] = arow[f * 4];
  }
  float s[4][4] = {};
  const float C1 = 14.4269504088896341f;  // 10*log2(e); exp(10d-10)=exp2(d*C1-C1)
  const int sw = l16 & 7;

  for (int g = 0; g < 16; ++g) {
    __syncthreads();
    stage_b32(Xn + (size_t)(nb0 + g * 32) * DIM, Bt, wave, lane);
    __syncthreads();
#pragma unroll
    for (int u = 0; u < 2; ++u) {
      const unsigned short* bt = Bt + (u * 16 + l16) * DIM;
      f32x4 acc[4] = {{0.f, 0.f, 0.f, 0.f}, {0.f, 0.f, 0.f, 0.f},
                      {0.f, 0.f, 0.f, 0.f}, {0.f, 0.f, 0.f, 0.f}};
#pragma unroll
      for (int f = 0; f < 8; ++f) {
        short8 b = *(const short8*)(bt + ((((f << 2) + quad) ^ sw) << 3));
#pragma unroll
        for (int t = 0; t < 4; ++t)
          acc[t] = __builtin_amdgcn_mfma_f32_16x16x32_bf16(a[t][f], b, acc[t], 0, 0, 0);
      }
#pragma unroll
      for (int t = 0; t < 4; ++t)
#pragma unroll
        for (int i = 0; i < 4; ++i)
          s[t][i] += exp2f(fmaf(acc[t][i], C1, -C1));
    }
  }
#pragma unroll
  for (int m = 1; m < 16; m <<= 1)
#pragma unroll
    for (int t = 0; t < 4; ++t)
#pragma unroll
      for (int i = 0; i < 4; ++i) s[t][i] += __shfl_xor(s[t][i], m, 64);
  if (l16 == 0) {
#pragma unroll
    for (int t = 0; t < 4; ++t)
#pragma unroll
      for (int i = 0; i < 4; ++i)
        atomicAdd(&s_sum[qbase + t * 16 + quad * 4 + i], s[t][i]);
  }
}

// ---------------- per-stage: lse -> outer loss accumulator ----------------
__global__ __launch_bounds__(256) void lse_final_kernel(
    const float* __restrict__ s_sum, const float* __restrict__ pos,
    float* __restrict__ acc, int stage) {
  const int t = threadIdx.x;
  const int k = blockIdx.x * 256 + t;
  float v = 10.0f + __logf(s_sum[k]) - pos[k];
#pragma unroll
  for (int m = 1; m < 64; m <<= 1) v += __shfl_xor(v, m, 64);
  __shared__ float red[4];
  if ((t & 63) == 0) red[t >> 6] = v;
  __syncthreads();
  if (t == 0) atomicAdd(&acc[4 + stage], red[0] + red[1] + red[2] + red[3]);
}

// ---------------- per-stage: MFMA argmin (hi/lo split) + fp32 rescore + update ----------------
// Block owns 64 rows. dot(r,e) via 3 bf16 MFMAs (aH*bH + aH*bL + aL*bH).
// Rank by cbn[e] - 2*dot (rn is row-constant). Rows with top2 gap < margin get
// exact fp32 rescore with the proven (rn - 2d) + cbn formula. Then fused update.
__global__ __launch_bounds__(256, 2) void argmin_update_kernel(
    float* __restrict__ resid, const float* __restrict__ cb,
    const unsigned short* __restrict__ cbH, const unsigned short* __restrict__ cbL,
    const float* __restrict__ cbn, float* __restrict__ rnorm,
    unsigned short* rH, unsigned short* rL,
    float* __restrict__ xq, float* __restrict__ idxf, float* __restrict__ acc,
    unsigned short* __restrict__ Xn, int stage) {
  __shared__ __align__(16) unsigned short Bt[32768];  // 64 KB: [kf][s][ct][quad][l16] 16B chunks
  __shared__ float sV1[4][64];
  __shared__ float sV2[4][64];
  __shared__ int   sIx[4][64];
  __shared__ int   sIdx[64];
  __shared__ int   sFlag[64];
  __shared__ float sred[4];
  const int tid  = threadIdx.x;
  const int lane = tid & 63;
  const int wave = tid >> 6;
  const int quad = lane >> 4;
  const int l16  = lane & 15;
  const int rbase = blockIdx.x * 64;

  f32x4 acc4[4][4];  // [rt][ct] : rows rt*16+quad*4+i, e (wave*4+ct)*16+l16
#pragma unroll
  for (int rt = 0; rt < 4; ++rt)
#pragma unroll
    for (int ct = 0; ct < 4; ++ct) acc4[rt][ct] = (f32x4){0.f, 0.f, 0.f, 0.f};

  for (int kc = 0; kc < 4; ++kc) {
    __syncthreads();  // waves done reading Bt (previous chunk)
    // stage codebook k-window [kc*64, kc*64+64) both splits: 4096 chunks of 16B
#pragma unroll
    for (int i = 0; i < 16; ++i) {
      const int p = i * 256 + tid;
      const int kf = p >> 11, s = (p >> 10) & 1, ctd = (p >> 6) & 15;
      const int qd = (p >> 4) & 3, ld = p & 15;
      const unsigned short* base = s ? cbL : cbH;
      const unsigned short* g =
          base + (size_t)(ctd * 16 + ld) * DIM + kc * 64 + kf * 32 + qd * 8;
      unsigned short* ldst = Bt + (i * 256 + wave * 64) * 8;
      __builtin_amdgcn_global_load_lds((glb_u32*)g, (lds_u32*)ldst, 16, 0, 0);
    }
    // A fragments (global, per-lane): rows rbase+rt*16+l16, k = kc*64+kf*32+quad*8
    short8 aH[4][2], aL[4][2];
#pragma unroll
    for (int rt = 0; rt < 4; ++rt)
#pragma unroll
      for (int kf = 0; kf < 2; ++kf) {
        const size_t off = (size_t)(rbase + rt * 16 + l16) * DIM + kc * 64 + kf * 32 + quad * 8;
        aH[rt][kf] = *(const short8*)(rH + off);
        aL[rt][kf] = *(const short8*)(rL + off);
      }
    __syncthreads();  // staging landed
#pragma unroll
    for (int kf = 0; kf < 2; ++kf)
#pragma unroll
      for (int ct = 0; ct < 4; ++ct) {
        const int ctg = wave * 4 + ct;
        short8 bH = *(const short8*)(Bt + (((kf * 2 + 0) * 64 + ctg * 4 + quad) * 16 + l16) * 8);
        short8 bL = *(const short8*)(Bt + (((kf * 2 + 1) * 64 + ctg * 4 + quad) * 16 + l16) * 8);
#pragma unroll
        for (int rt = 0; rt < 4; ++rt) {
          acc4[rt][ct] = __builtin_amdgcn_mfma_f32_16x16x32_bf16(aL[rt][kf], bH, acc4[rt][ct], 0, 0, 0);
          acc4[rt][ct] = __builtin_amdgcn_mfma_f32_16x16x32_bf16(aH[rt][kf], bL, acc4[rt][ct], 0, 0, 0);
          acc4[rt][ct] = __builtin_amdgcn_mfma_f32_16x16x32_bf16(aH[rt][kf], bH, acc4[rt][ct], 0, 0, 0);
        }
      }
  }

  // ---- epilogue: per-row top-2 over this wave's 64 e ----
  float cbe[4];
#pragma unroll
  for (int ct = 0; ct < 4; ++ct) cbe[ct] = cbn[(wave * 4 + ct) * 16 + l16];
#pragma unroll
  for (int rt = 0; rt < 4; ++rt) {
    float b1[4], b2[4]; int e1[4];
#pragma unroll
    for (int i = 0; i < 4; ++i) { b1[i] = 3.4e38f; b2[i] = 3.4e38f; e1[i] = 0; }
#pragma unroll
    for (int ct = 0; ct < 4; ++ct) {
      const int e = (wave * 4 + ct) * 16 + l16;
#pragma unroll
      for (int i = 0; i < 4; ++i) {
        const float v = fmaf(-2.0f, acc4[rt][ct][i], cbe[ct]);
        if (v < b1[i]) { b2[i] = b1[i]; b1[i] = v; e1[i] = e; }
        else if (v < b2[i]) b2[i] = v;
      }
    }
#pragma unroll
    for (int m = 1; m < 16; m <<= 1) {
#pragma unroll
      for (int i = 0; i < 4; ++i) {
        const float o1 = __shfl_xor(b1[i], m, 64);
        const float o2 = __shfl_xor(b2[i], m, 64);
        const int   oe = __shfl_xor(e1[i], m, 64);
        if (o1 < b1[i] || (o1 == b1[i] && oe < e1[i])) {
          b2[i] = fminf(b1[i], o2); b1[i] = o1; e1[i] = oe;
        } else {
          b2[i] = fminf(b2[i], o1);
        }
      }
    }
    if (l16 == 0) {
#pragma unroll
      for (int i = 0; i < 4; ++i) {
        const int r = rt * 16 + quad * 4 + i;
        sV1[wave][r] = b1[i]; sV2[wave][r] = b2[i]; sIx[wave][r] = e1[i];
      }
    }
  }
  __syncthreads();
  if (tid < 64) {
    float v1 = 3.4e38f, v2 = 3.4e38f; int ix = 0;
#pragma unroll
    for (int w = 0; w < 4; ++w) {
      const float a1 = sV1[w][tid], a2 = sV2[w][tid];
      const int ae = sIx[w][tid];
      if (a1 < v1) { v2 = fminf(v1, a2); v1 = a1; ix = ae; }
      else { v2 = fminf(v2, fminf(a1, a2)); }
    }
    sIdx[tid] = ix;
    sFlag[tid] = (v2 - v1 < RESCORE_MARGIN) ? 1 : 0;
  }
  __syncthreads();

  // ---- exact fp32 rescore for flagged rows (rare) ----
  for (int rr = 0; rr < 16; ++rr) {
    const int r = wave * 16 + rr;
    if (sFlag[r]) {
      const int row = rbase + r;
      const float* rrow = resid + (size_t)row * DIM;
      float d[4] = {0.f, 0.f, 0.f, 0.f};
      for (int kb = 0; kb < 64; ++kb) {
        const float4 rv = ((const float4*)rrow)[kb];
#pragma unroll
        for (int j = 0; j < 4; ++j) {
          const float4 cv = ((const float4*)(cb + (size_t)(lane + 64 * j) * DIM))[kb];
          d[j] = fmaf(rv.x, cv.x, d[j]);
          d[j] = fmaf(rv.y, cv.y, d[j]);
          d[j] = fmaf(rv.z, cv.z, d[j]);
          d[j] = fmaf(rv.w, cv.w, d[j]);
        }
      }
      const float rn = rnorm[row];
      float bv = 3.4e38f; int be = 0;
#pragma unroll
      for (int j = 0; j < 4; ++j) {
        const int e = lane + 64 * j;
        const float v = (rn - 2.0f * d[j]) + cbn[e];
        if (v < bv) { bv = v; be = e; }
      }
#pragma unroll
      for (int m = 1; m < 64; m <<= 1) {
        const float vo = __shfl_xor(bv, m, 64);
        const int   eo = __shfl_xor(be, m, 64);
        if (vo < bv || (vo == bv && eo < be)) { bv = vo; be = eo; }
      }
      if (lane == 0) sIdx[r] = be;
    }
  }
  __syncthreads();

  // ---- update phase: wave per row, 16 passes ----
  float msum = 0.0f;
  for (int i = 0; i < 16; ++i) {
    const int rr = i * 4 + wave;
    const int row = rbase + rr;
    const int e = sIdx[rr];
    float4 r4 = ((const float4*)(resid + (size_t)row * DIM))[lane];
    float4 q4 = ((const float4*)(cb + (size_t)e * DIM))[lane];
    float4 nr = {r4.x - q4.x, r4.y - q4.y, r4.z - q4.z, r4.w - q4.w};
    float ss = nr.x * nr.x + nr.y * nr.y + nr.z * nr.z + nr.w * nr.w;
    float4* xp = (float4*)(xq + (size_t)row * DIM) + lane;
    if (stage == 0) {
      *xp = q4;
    } else {
      float4 o = *xp;
      o.x += q4.x; o.y += q4.y; o.z += q4.z; o.w += q4.w;
      *xp = o;
    }
#pragma unroll
    for (int m = 1; m < 64; m <<= 1) ss += __shfl_xor(ss, m, 64);
    if (stage < 3) {
      ((float4*)(resid + (size_t)row * DIM))[lane] = nr;
      ushort4 h, l;
      h.x = f2bf(nr.x); l.x = f2bf(nr.x - bf2f(h.x));
      h.y = f2bf(nr.y); l.y = f2bf(nr.y - bf2f(h.y));
      h.z = f2bf(nr.z); l.z = f2bf(nr.z - bf2f(h.z));
      h.w = f2bf(nr.w); l.w = f2bf(nr.w - bf2f(h.w));
      ((ushort4*)(rH + (size_t)row * DIM))[lane] = h;
      ((ushort4*)(rL + (size_t)row * DIM))[lane] = l;
      const float sc = rsqrtf(ss + 1e-12f);
      ushort4 o;
      o.x = f2bf(nr.x * sc); o.y = f2bf(nr.y * sc);
      o.z = f2bf(nr.z * sc); o.w = f2bf(nr.w * sc);
      ((ushort4*)(Xn + (size_t)row * DIM))[lane] = o;
      if (lane == 0) rnorm[row] = ss;
    }
    if (lane == 0) {
      idxf[(size_t)row * NQ + stage] = (float)e;
      msum += ss;
    }
  }
  if (lane == 0) sred[wave] = msum;
  __syncthreads();
  if (tid == 0) atomicAdd(&acc[0], sred[0] + sred[1] + sred[2] + sred[3]);
}

// ---------------- finalize scalar outputs ----------------
__global__ void finalize_kernel(const float* __restrict__ acc, float* __restrict__ out) {
  const int t = threadIdx.x;
  if (t == 0) out[ND] = acc[0] * (1.25f / (4.0f * (float)ND));
  if (t < 4) out[ND + 1 + t] = acc[4 + t] * (1.0f / (float)KP);
}

extern "C" void kernel_launch(void* const* d_in, const int* in_sizes, int n_in,
                              void* d_out, int out_size, void* d_ws, size_t ws_size,
                              hipStream_t stream) {
  const float* x         = (const float*)d_in[0];
  const float* codebooks = (const float*)d_in[1];
  const int*   i1        = (const int*)d_in[2];
  const int*   i2        = (const int*)d_in[3];
  float* out = (float*)d_out;
  float* out_xq   = out;                 // [N, D]
  float* out_idxf = out + ND + 1 + NQ;   // [N, NQ] as float

  char* w = (char*)d_ws;
  float*          resid = (float*)w;          w += (size_t)N_ROWS * DIM * 4;
  unsigned short* Xn    = (unsigned short*)w; w += (size_t)N_ROWS * DIM * 2;
  unsigned short* rH    = (unsigned short*)w; w += (size_t)N_ROWS * DIM * 2;
  unsigned short* rL    = (unsigned short*)w; w += (size_t)N_ROWS * DIM * 2;
  float*          rnorm = (float*)w;          w += (size_t)N_ROWS * 4;
  unsigned short* Qg    = (unsigned short*)w; w += (size_t)KP * DIM * 2;
  float*          pos   = (float*)w;          w += (size_t)KP * 4;
  float*          ssum  = (float*)w;          w += (size_t)KP * 4;
  float*          cbn   = (float*)w;          w += (size_t)NQ * NE * 4;
  unsigned short* cbH   = (unsigned short*)w; w += (size_t)NQ * NE * DIM * 2;
  unsigned short* cbL   = (unsigned short*)w; w += (size_t)NQ * NE * DIM * 2;
  float*          acc   = (float*)w;          w += 32;  // [0]=sumsq, [4..7]=outer sums

  prep0_kernel<<<8192, 256, 0, stream>>>(x, resid, Xn, rnorm, rH, rL);
  cbnorm_kernel<<<256, 256, 0, stream>>>(codebooks, cbn);
  cbsplit_kernel<<<256, 256, 0, stream>>>(codebooks, cbH, cbL);
  hipMemsetAsync(acc, 0, 32, stream);
  for (int q = 0; q < NQ; ++q) {
    const float* cb = codebooks + (size_t)q * NE * DIM;
    gather_pos_kernel<<<1024, 256, 0, stream>>>(Xn, i1, i2, Qg, pos, ssum);
    sim_lse_kernel<<<dim3(16, 64), 256, 0, stream>>>(Qg, Xn, ssum);
    lse_final_kernel<<<16, 256, 0, stream>>>(ssum, pos, acc, q);
    argmin_update_kernel<<<512, 256, 0, stream>>>(
        resid, cb, cbH + (size_t)q * NE * DIM, cbL + (size_t)q * NE * DIM,
        cbn + q * NE, rnorm, rH, rL, out_xq, out_idxf, acc, Xn, q);
  }
  finalize_kernel<<<1, 64, 0, stream>>>(acc, out);
}